// Round 10
// baseline (451.679 us; speedup 1.0000x reference)
//
#include <hip/hip_runtime.h>
#include <hip/hip_bf16.h>
#include <math.h>
#include <stdint.h>

typedef __bf16 bf16;
typedef __bf16 bf16x8 __attribute__((ext_vector_type(8)));
typedef __bf16 bf16x4 __attribute__((ext_vector_type(4)));
typedef float  f32x4  __attribute__((ext_vector_type(4)));

#define NTASKS 10
#define CAP    3
#define SEQ    128
#define HID    768
#define ADAPT  2048
#define BATCH  128
#define BL     (BATCH*SEQ)   /* 16384 */
#define NEGV   (-10000.0f)

__device__ __forceinline__ float sigmoidf_(float z) { return 1.f / (1.f + expf(-z)); }

// ---- async global->LDS, 16B per lane; LDS dest = wave-uniform base + lane*16 ----
__device__ __forceinline__ void gld16(const void* g, void* l) {
    auto gp = (const __attribute__((address_space(1))) uint32_t*)g;
    auto lp = (__attribute__((address_space(3))) uint32_t*)(uint32_t)(uintptr_t)l;
    __builtin_amdgcn_global_load_lds(gp, lp, 16, 0, 0);
}

// ---------------- gates: sigmoid(s * e*) ----------------
__global__ void k_gates(const float* efc1, const float* efc2, const float* elarger,
                        const float* s, const int* tptr,
                        float* gfc1, float* gfc2, float* glarger) {
    int i = blockIdx.x * 256 + threadIdx.x;
    int t = *tptr; float sv = *s;
    if (i < ADAPT)                gfc1[i] = sigmoidf_(sv * efc1[t * ADAPT + i]);
    else if (i < ADAPT + HID)     { int j = i - ADAPT;        gfc2[j]    = sigmoidf_(sv * efc2[t * HID + j]); }
    else if (i < ADAPT + 2 * HID) { int j = i - ADAPT - HID;  glarger[j] = sigmoidf_(sv * elarger[t * HID + j]); }
}

// ---- fuse semantic fc1+fc2 into bf16 Wb[32][768] (rows 30,31 zero) + f32 bb[32] ----
__global__ void k_fusew(const float* sfc1_w, const float* sfc1_b,
                        const float* sfc2_w, const float* sfc2_b,
                        bf16* Wb, float* bb) {
    int j = blockIdx.x;        // 0..31
    int n = j / CAP;
    if (j >= 30) {
        for (int i = threadIdx.x; i < HID; i += 256) Wb[j * HID + i] = (bf16)0.f;
        if (threadIdx.x == 0) bb[j] = 0.f;
        return;
    }
    __shared__ float w2[100];
    if (threadIdx.x < 100) w2[threadIdx.x] = sfc2_w[j * 100 + threadIdx.x];
    __syncthreads();
    const float* w1 = sfc1_w + (size_t)n * 100 * HID;
    float a0 = 0, a1 = 0, a2 = 0;
    for (int k = 0; k < 100; ++k) {
        float s2 = w2[k];
        const float* r = w1 + k * HID;
        a0 += s2 * r[threadIdx.x];
        a1 += s2 * r[threadIdx.x + 256];
        a2 += s2 * r[threadIdx.x + 512];
    }
    Wb[j * HID + threadIdx.x]       = (bf16)a0;
    Wb[j * HID + threadIdx.x + 256] = (bf16)a1;
    Wb[j * HID + threadIdx.x + 512] = (bf16)a2;
    if (threadIdx.x == 0) {
        float b = sfc2_b[j];
        for (int k = 0; k < 100; ++k) b += sfc1_b[n * 100 + k] * w2[k];
        bb[j] = b;
    }
}

// ---------------- fp32 -> bf16 weight conversion ----------------
__global__ void k_convert(const float* fc1_w, const float* fc2_w, bf16* B1, bf16* B2) {
    int i = blockIdx.x * 256 + threadIdx.x;
    const int quarter = ADAPT * HID / 4;  // 393216 float4's per weight
    if (i < quarter) {
        float4 v = ((const float4*)fc1_w)[i];
        bf16x4 o = { (bf16)v.x, (bf16)v.y, (bf16)v.z, (bf16)v.w };
        ((bf16x4*)B1)[i] = o;
    } else if (i < 2 * quarter) {
        int j = i - quarter;
        float4 v = ((const float4*)fc2_w)[j];
        bf16x4 o = { (bf16)v.x, (bf16)v.y, (bf16)v.z, (bf16)v.w };
        ((bf16x4*)B2)[j] = o;
    }
}

// ---- transpose-convert route_weights: rwb[cn][l][d] = bf16(rw[cn][d][l]) ----
__global__ void k_rwT(const float* __restrict__ rw, bf16* __restrict__ rwb) {
    int cn = blockIdx.x;           // 0..29
    int d0 = blockIdx.y * 64;      // 6 tiles of 64 d
    __shared__ float t[64][129];
    const float* src = rw + (size_t)cn * 384 * 128;
    int tid = threadIdx.x;         // 256
    #pragma unroll
    for (int p = 0; p < 8; ++p) {
        int f4 = tid + p * 256;    // 2048 float4 per tile
        int row = f4 >> 5, c4 = (f4 & 31) * 4;
        float4 v = *(const float4*)(src + (size_t)(d0 + row) * 128 + c4);
        t[row][c4] = v.x; t[row][c4 + 1] = v.y; t[row][c4 + 2] = v.z; t[row][c4 + 3] = v.w;
    }
    __syncthreads();
    bf16* dst = rwb + (size_t)cn * 128 * 384 + d0;
    #pragma unroll
    for (int p = 0; p < 4; ++p) {
        int i8 = tid + p * 256;    // 1024 bf16x8 per tile
        int l = i8 >> 3, d8 = (i8 & 7) * 8;
        bf16x8 o;
        #pragma unroll
        for (int i = 0; i < 8; ++i) o[i] = (bf16)t[d8 + i][l];
        *(bf16x8*)(dst + (size_t)l * 384 + d8) = o;
    }
}

// ---------------- semantic caps via MFMA + fused squash -> bf16 semb[n][b][384] ----------------
__launch_bounds__(256)
__global__ void k_semg(const float* __restrict__ x, const bf16* __restrict__ Wb,
                       const float* __restrict__ bb, bf16* __restrict__ semb) {
    __shared__ __align__(16) bf16 As[64 * 32];
    __shared__ __align__(16) bf16 Bs[32 * 32];
    __shared__ float sem_s[64][33];
    const int tid = threadIdx.x;
    const int wave = tid >> 6, lane = tid & 63;
    const int tm = blockIdx.x;
    const int lr = lane & 15, kg = (lane >> 4) * 8;
    f32x4 acc[2] = {};

    const float* xbase = x + (size_t)(tm * 64 + (tid >> 2)) * HID + (tid & 3) * 8;
    const bf16* wbase = Wb + (size_t)(tid >> 2) * HID + (tid & 3) * 8;  // valid for tid<128
    bf16* BsW = Bs + wave * 512;

    for (int k0 = 0; k0 < HID; k0 += 32) {
        float xv[8];
        *(float4*)&xv[0] = *(const float4*)(xbase + k0);
        *(float4*)&xv[4] = *(const float4*)(xbase + k0 + 4);
        __syncthreads();
        if (tid < 128) gld16(wbase + k0, BsW);
        bf16x8 xb;
        #pragma unroll
        for (int i = 0; i < 8; ++i) xb[i] = (bf16)xv[i];
        *(bf16x8*)&As[tid * 8] = xb;
        __syncthreads();
        bf16x8 af = *(const bf16x8*)&As[(wave * 16 + lr) * 32 + kg];
        bf16x8 b0 = *(const bf16x8*)&Bs[lr * 32 + kg];
        bf16x8 b1 = *(const bf16x8*)&Bs[(16 + lr) * 32 + kg];
        acc[0] = __builtin_amdgcn_mfma_f32_16x16x32_bf16(af, b0, acc[0], 0, 0, 0);
        acc[1] = __builtin_amdgcn_mfma_f32_16x16x32_bf16(af, b1, acc[1], 0, 0, 0);
    }

    #pragma unroll
    for (int n = 0; n < 2; ++n) {
        int col = n * 16 + lr;
        float bv = bb[col];
        #pragma unroll
        for (int r = 0; r < 4; ++r) {
            int row = wave * 16 + (lane >> 4) * 4 + r;
            sem_s[row][col] = acc[n][r] + bv;
        }
    }
    __syncthreads();
    if (tid < 64) {
        int bl = tm * 64 + tid;
        int b = bl >> 7, l = bl & 127;
        float vals[30];
        float sq[3] = {0.f, 0.f, 0.f};
        #pragma unroll
        for (int j = 0; j < 30; ++j) { float v = sem_s[tid][j]; vals[j] = v; sq[j % 3] += v * v; }
        float scl[3];
        #pragma unroll
        for (int c = 0; c < 3; ++c) scl[c] = (sq[c] / (1.f + sq[c])) / sqrtf(sq[c]);
        #pragma unroll
        for (int j = 0; j < 30; ++j)
            semb[((size_t)(j / 3) * BATCH + b) * 384 + l * 3 + (j % 3)] = (bf16)(vals[j] * scl[j % 3]);
    }
}

// ---------------- priors via MFMA: 30 blocks of 128x128x384 ----------------
__launch_bounds__(256)
__global__ void k_priorsG(const bf16* __restrict__ semb, const bf16* __restrict__ rwb,
                          float* __restrict__ priors) {
    __shared__ __align__(16) bf16 As[128 * 32];
    __shared__ __align__(16) bf16 Bs[128 * 32];
    const int cn = blockIdx.x;           // c*10+n
    const int c = cn / NTASKS, n = cn % NTASKS;
    const int tid = threadIdx.x;
    const int wave = tid >> 6, lane = tid & 63;
    const int wr = wave >> 1, wc = wave & 1;
    const int lr = lane & 15, kg = (lane >> 4) * 8;
    const int K = 384;
    f32x4 acc[4][4] = {};

    const bf16* Abase = semb + ((size_t)n * BATCH + (tid >> 2)) * K + (tid & 3) * 8;
    const bf16* Bbase = rwb + ((size_t)cn * 128 + (tid >> 2)) * K + (tid & 3) * 8;
    bf16* AsW = As + wave * 512;
    bf16* BsW = Bs + wave * 512;

    for (int k0 = 0; k0 < K; k0 += 32) {
        __syncthreads();
        gld16(Abase + k0, AsW);
        gld16(Abase + k0 + (size_t)64 * K, AsW + 2048);
        gld16(Bbase + k0, BsW);
        gld16(Bbase + k0 + (size_t)64 * K, BsW + 2048);
        __syncthreads();
        bf16x8 af[4], bfr[4];
        #pragma unroll
        for (int m = 0; m < 4; ++m)
            af[m] = *(const bf16x8*)&As[(wr * 64 + m * 16 + lr) * 32 + kg];
        #pragma unroll
        for (int nn = 0; nn < 4; ++nn)
            bfr[nn] = *(const bf16x8*)&Bs[(wc * 64 + nn * 16 + lr) * 32 + kg];
        #pragma unroll
        for (int m = 0; m < 4; ++m)
            #pragma unroll
            for (int nn = 0; nn < 4; ++nn)
                acc[m][nn] = __builtin_amdgcn_mfma_f32_16x16x32_bf16(af[m], bfr[nn], acc[m][nn], 0, 0, 0);
    }

    #pragma unroll
    for (int nn = 0; nn < 4; ++nn) {
        int col = wc * 64 + nn * 16 + lr;
        #pragma unroll
        for (int m = 0; m < 4; ++m) {
            int row0 = wr * 64 + m * 16 + (lane >> 4) * 4;
            #pragma unroll
            for (int r = 0; r < 4; ++r) {
                int row = row0 + r;
                priors[(((size_t)c * BATCH + row) * NTASKS + n) * 128 + col] = acc[m][nn][r];
            }
        }
    }
}

// ---------------- dynamic routing; logits are uniform over l ----------------
__global__ void k_routing(const float* __restrict__ priors, const int* tptr,
                          float* __restrict__ vote) {
    int cb = blockIdx.x;             // c*128+b
    int lane = threadIdx.x;          // 64
    int t = *tptr;
    float p0[NTASKS], p1[NTASKS], ln[NTASKS];
    const float* pb = priors + (size_t)cb * NTASKS * 128;
    #pragma unroll
    for (int n = 0; n < NTASKS; ++n) {
        p0[n] = pb[n * 128 + lane];
        p1[n] = pb[n * 128 + 64 + lane];
        ln[n] = 0.f;
    }
    float v0 = 0.f, v1 = 0.f;
    for (int it = 0; it < 3; ++it) {
        float lm[NTASKS];
        float mx = -3.4e38f;
        #pragma unroll
        for (int n = 0; n < NTASKS; ++n) { lm[n] = (n <= t) ? ln[n] : NEGV; mx = fmaxf(mx, lm[n]); }
        float e[NTASKS], se = 0.f;
        #pragma unroll
        for (int n = 0; n < NTASKS; ++n) { e[n] = expf(lm[n] - mx); se += e[n]; }
        float inv = 1.f / se;
        v0 = 0.f; v1 = 0.f;
        #pragma unroll
        for (int n = 0; n < NTASKS; ++n) { float pr = e[n] * inv; v0 += pr * p0[n]; v1 += pr * p1[n]; }
        if (it == 2) break;
        float sq = v0 * v0 + v1 * v1;
        #pragma unroll
        for (int m = 32; m >= 1; m >>= 1) sq += __shfl_xor(sq, m);
        float scale = (sq / (1.f + sq)) / sqrtf(sq);
        float o0 = v0 * scale, o1 = v1 * scale;
        #pragma unroll
        for (int n = 0; n < NTASKS; ++n) {
            float d = p0[n] * o0 + p1[n] * o1;
            #pragma unroll
            for (int m = 32; m >= 1; m >>= 1) d += __shfl_xor(d, m);
            ln[n] = lm[n] + d;
        }
    }
    vote[(size_t)cb * 128 + lane]      = v0;
    vote[(size_t)cb * 128 + 64 + lane] = v1;
}

// ---------------- h = x + (scrambled_vote @ larger_w^T + larger_b) * glarger  -> bf16 ----------------
__global__ void k_buildH(const float* __restrict__ x, const float* __restrict__ vote,
                         const float* __restrict__ lw, const float* __restrict__ lb,
                         const float* __restrict__ glarger, bf16* __restrict__ H) {
    int idx = blockIdx.x * 256 + threadIdx.x;   // over BL*192 float4 groups
    int bl = idx / 192, h4 = (idx % 192) * 4;
    float v0 = vote[bl * 3 + 0], v1 = vote[bl * 3 + 1], v2 = vote[bl * 3 + 2];
    float xa[4];
    *(float4*)xa = ((const float4*)x)[idx];
    bf16x4 o;
    #pragma unroll
    for (int r = 0; r < 4; ++r) {
        int hid = h4 + r;
        float hv = v0 * lw[hid * 3] + v1 * lw[hid * 3 + 1] + v2 * lw[hid * 3 + 2] + lb[hid];
        o[r] = (bf16)(xa[r] + hv * glarger[hid]);
    }
    ((bf16x4*)H)[idx] = o;
}

// ====== 128x256 BK=32 GEMM, 8 waves, next-tile-reads ∥ MFMA, 3 bufs, 2 blk/CU ======
// Iter T: [stage T+2] [vmcnt(3): drain T+1's stage, keep T+2 in flight]
//         [lgkmcnt(0): tile-T frag reads (issued last iter) done -> re-stage safe]
//         [barrier] [issue tile T+1's 8 ds_reads] [MFMA tile T — no wait, overlaps]
// 3 bufs x 24KB = 72KB -> 2 blocks/CU. One barrier/iter. NT must be EVEN.
// Swizzle (r7-verified, 0 conflicts): source chunk (lane&3)^((lane>>3)&3),
// read slot kq^((lr>>1)&3).
// MODE 1: Out = bf16 [M][N].  MODE 2: Out = f32, Out = X + val, N==HID.
template <int MODE>
__launch_bounds__(512, 4)
__global__ void k_gemmQ(const bf16* __restrict__ A, const bf16* __restrict__ Bw,
                        const float* __restrict__ bias, const float* __restrict__ gate,
                        const float* __restrict__ X, void* __restrict__ Out,
                        int K, int N, int TN, int NT) {
    __shared__ __align__(16) char smem[73728];   // 3 bufs x (A 8KB + B 16KB)
    const int tid = threadIdx.x;
    const int lane = tid & 63, w = tid >> 6;
    const int lr = lane & 15, kq = lane >> 4;
    const int qr = w >> 2, qc = w & 3;              // wave grid 2x4, wave tile 64x64
    const int nwg = gridDim.x, bid = blockIdx.x;
    const int cpx = nwg >> 3;                       // grid % 8 == 0 for all calls
    const int wg = (bid & 7) * cpx + (bid >> 3);
    const int tm = wg / TN, tn = wg % TN;

    const int srow = lane >> 2;
    const int schunk = (lane & 3) ^ ((lane >> 3) & 3);
    const bf16* Ab  = A  + (size_t)(tm * 128 + w * 16 + srow) * K + schunk * 8;
    const bf16* Bb0 = Bw + (size_t)(tn * 256 + w * 16 + srow) * K + schunk * 8;
    const bf16* Bb1 = Bb0 + (size_t)128 * K;
    auto stage = [&](int k0, int off) {             // 3 gld16/wave, 24KB/block
        gld16(Ab  + k0, smem + off + w * 1024);
        gld16(Bb0 + k0, smem + off + 8192 + w * 1024);
        gld16(Bb1 + k0, smem + off + 16384 + w * 1024);
    };

    const int rsl = (kq ^ ((lr >> 1) & 3)) << 4;    // read-side swizzled 16B slot
    f32x4 acc[4][4] = {};
    bf16x8 aA[4], bA[4], aB[4], bB[4];

#define RD8(OFF, ASET, BSET)                                                       \
    {                                                                              \
        const char* ab_ = smem + (OFF);                                            \
        const char* bb_ = smem + (OFF) + 8192;                                     \
        _Pragma("unroll")                                                          \
        for (int m = 0; m < 4; ++m)                                                \
            ASET[m] = *(const bf16x8*)(ab_ + (qr * 64 + m * 16 + lr) * 64 + rsl);  \
        _Pragma("unroll")                                                          \
        for (int n = 0; n < 4; ++n)                                                \
            BSET[n] = *(const bf16x8*)(bb_ + (qc * 64 + n * 16 + lr) * 64 + rsl);  \
    }

    // prologue: stage tiles 0,1; drain tile 0; read tile-0 frags
    stage(0, 0);
    stage(32, 24576);
    asm volatile("s_waitcnt vmcnt(3)" ::: "memory");
    __builtin_amdgcn_s_barrier();
    RD8(0, aA, bA);

    int offS = 49152;   // buf for stage of tile T+2
    int offR = 24576;   // buf holding tile T+1 (frag reads)

#define STEP(T, CA, CB, NA, NB)                                                    \
    {                                                                              \
        const int t_ = (T);                                                        \
        if (t_ + 2 < NT) {                                                         \
            stage((t_ + 2) * 32, offS);                                            \
            asm volatile("s_waitcnt vmcnt(3)" ::: "memory");                       \
        } else {                                                                   \
            asm volatile("s_waitcnt vmcnt(0)" ::: "memory");                       \
        }                                                                          \
        asm volatile("s_waitcnt lgkmcnt(0)" ::: "memory");                         \
        __builtin_amdgcn_s_barrier();                                              \
        if (t_ + 1 < NT) RD8(offR, NA, NB);                                        \
        __builtin_amdgcn_sched_barrier(0);                                         \
        __builtin_amdgcn_s_setprio(1);                                             \
        _Pragma("unroll")                                                          \
        for (int m = 0; m < 4; ++m)                                                \
            _Pragma("unroll")                                                      \
            for (int n = 0; n < 4; ++n)                                            \
                acc[m][n] = __builtin_amdgcn_mfma_f32_16x16x32_bf16(               \
                    CA[m], CB[n], acc[m][n], 0, 0, 0);                             \
        __builtin_amdgcn_s_setprio(0);                                             \
        offS += 24576; if (offS >= 73728) offS = 0;                                \
        offR += 24576; if (offR >= 73728) offR = 0;                                \
    }

    for (int T = 0; T < NT; T += 2) {       // NT even (24 / 64)
        STEP(T,     aA, bA, aB, bB);
        STEP(T + 1, aB, bB, aA, bA);
    }
#undef STEP
#undef RD8

    #pragma unroll
    for (int n = 0; n < 4; ++n) {
        int col = tn * 256 + qc * 64 + n * 16 + lr;
        float bv = bias[col], gv = gate[col];
        #pragma unroll
        for (int m = 0; m < 4; ++m) {
            int row0 = tm * 128 + qr * 64 + m * 16 + kq * 4;
            #pragma unroll
            for (int r = 0; r < 4; ++r) {
                float v = fmaxf(acc[m][n][r] + bv, 0.f) * gv;
                int row = row0 + r;
                if (MODE == 1) {
                    ((bf16*)Out)[(size_t)row * N + col] = (bf16)v;
                } else {
                    size_t o = (size_t)row * HID + col;
                    ((float*)Out)[o] = X[o] + v;
                }
            }
        }
    }
}

extern "C" void kernel_launch(void* const* d_in, const int* in_sizes, int n_in,
                              void* d_out, int out_size, void* d_ws, size_t ws_size,
                              hipStream_t stream) {
    const float* x      = (const float*)d_in[0];
    const int*   t      = (const int*)  d_in[1];
    const float* s      = (const float*)d_in[2];
    const float* fc1_w  = (const float*)d_in[3];
    const float* fc1_b  = (const float*)d_in[4];
    const float* fc2_w  = (const float*)d_in[5];
    const float* fc2_b  = (const float*)d_in[6];
    const float* efc1   = (const float*)d_in[7];
    const float* efc2   = (const float*)d_in[8];
    const float* sfc1_w = (const float*)d_in[9];
    const float* sfc1_b = (const float*)d_in[10];
    const float* sfc2_w = (const float*)d_in[11];
    const float* sfc2_b = (const float*)d_in[12];
    const float* rw     = (const float*)d_in[13];
    const float* lw     = (const float*)d_in[14];
    const float* lb     = (const float*)d_in[15];
    const float* elarger= (const float*)d_in[16];

    char* ws = (char*)d_ws;
    size_t off = 0;
    auto alloc = [&](size_t b) { void* p = ws + off; off = (off + b + 255) & ~(size_t)255; return p; };
    float* gfc1    = (float*)alloc(ADAPT * 4);
    float* gfc2    = (float*)alloc(HID * 4);
    float* glarger = (float*)alloc(HID * 4);
    bf16*  Wb      = (bf16*) alloc(32 * HID * 2);
    float* bb      = (float*)alloc(32 * 4);
    bf16*  B1      = (bf16*) alloc((size_t)ADAPT * HID * 2);
    bf16*  B2      = (bf16*) alloc((size_t)ADAPT * HID * 2);
    bf16*  semb    = (bf16*) alloc((size_t)NTASKS * BATCH * 384 * 2);
    bf16*  rwb     = (bf16*) alloc((size_t)30 * 128 * 384 * 2);
    float* priors  = (float*)alloc((size_t)CAP * BATCH * NTASKS * 128 * 4);
    float* vote    = (float*)alloc((size_t)CAP * BATCH * 128 * 4);
    bf16*  H1      = (bf16*) alloc((size_t)BL * ADAPT * 2);
    bf16*  H       = (bf16*)d_out;  // stage bf16 h in the (larger) output buffer

    k_gates  <<<14, 256, 0, stream>>>(efc1, efc2, elarger, s, t, gfc1, gfc2, glarger);
    k_fusew  <<<32, 256, 0, stream>>>(sfc1_w, sfc1_b, sfc2_w, sfc2_b, Wb, bb);
    k_convert<<<3072, 256, 0, stream>>>(fc1_w, fc2_w, B1, B2);
    k_rwT    <<<dim3(30, 6), 256, 0, stream>>>(rw, rwb);
    k_semg   <<<BL / 64, 256, 0, stream>>>(x, Wb, bb, semb);
    k_priorsG<<<30, 256, 0, stream>>>(semb, rwb, priors);
    k_routing<<<CAP * BATCH, 64, 0, stream>>>(priors, t, vote);
    k_buildH <<<BL * 192 / 256, 256, 0, stream>>>(x, vote, lw, lb, glarger, H);
    // GEMM1: [16384x768] @ [2048x768]^T -> H1 (bf16)   grid 128*8=1024, NT=24
    k_gemmQ<1><<<1024, 512, 0, stream>>>(H,  B1, fc1_b, gfc1, nullptr, H1,   HID,   ADAPT, 8, HID / 32);
    // GEMM2: [16384x2048] @ [768x2048]^T + x -> out    grid 128*3=384, NT=64
    k_gemmQ<2><<<384, 512, 0, stream>>>(H1, B2, fc2_b, gfc2, x,       d_out, ADAPT, HID,  3, ADAPT / 32);
}

// Round 11
// 322.011 us; speedup vs baseline: 1.4027x; 1.4027x over previous
//
#include <hip/hip_runtime.h>
#include <hip/hip_bf16.h>
#include <math.h>
#include <stdint.h>

typedef __bf16 bf16;
typedef __bf16 bf16x8 __attribute__((ext_vector_type(8)));
typedef __bf16 bf16x4 __attribute__((ext_vector_type(4)));
typedef float  f32x4  __attribute__((ext_vector_type(4)));

#define NTASKS 10
#define CAP    3
#define SEQ    128
#define HID    768
#define ADAPT  2048
#define BATCH  128
#define BL     (BATCH*SEQ)   /* 16384 */
#define NEGV   (-10000.0f)

__device__ __forceinline__ float sigmoidf_(float z) { return 1.f / (1.f + expf(-z)); }

// ---- async global->LDS, 16B per lane; LDS dest = wave-uniform base + lane*16 ----
__device__ __forceinline__ void gld16(const void* g, void* l) {
    auto gp = (const __attribute__((address_space(1))) uint32_t*)g;
    auto lp = (__attribute__((address_space(3))) uint32_t*)(uint32_t)(uintptr_t)l;
    __builtin_amdgcn_global_load_lds(gp, lp, 16, 0, 0);
}

// ========== fused prep: convert(3072) | rwT(180) | fusew(32) | gates(14) ==========
__global__ void k_prep(const float* __restrict__ fc1_w, const float* __restrict__ fc2_w,
                       bf16* __restrict__ B1, bf16* __restrict__ B2,
                       const float* __restrict__ rw, bf16* __restrict__ rwb,
                       const float* __restrict__ sfc1_w, const float* __restrict__ sfc1_b,
                       const float* __restrict__ sfc2_w, const float* __restrict__ sfc2_b,
                       bf16* __restrict__ Wb, float* __restrict__ bb,
                       const float* __restrict__ efc1, const float* __restrict__ efc2,
                       const float* __restrict__ elarger, const float* __restrict__ s,
                       const int* __restrict__ tptr,
                       float* __restrict__ gfc1, float* __restrict__ gfc2,
                       float* __restrict__ glarger) {
    __shared__ float shbuf[64 * 129];
    const int bid = blockIdx.x, tid = threadIdx.x;
    if (bid < 3072) {
        // ---- fp32 -> bf16 weight conversion ----
        int i = bid * 256 + tid;
        const int quarter = ADAPT * HID / 4;
        if (i < quarter) {
            float4 v = ((const float4*)fc1_w)[i];
            bf16x4 o = { (bf16)v.x, (bf16)v.y, (bf16)v.z, (bf16)v.w };
            ((bf16x4*)B1)[i] = o;
        } else {
            int j = i - quarter;
            float4 v = ((const float4*)fc2_w)[j];
            bf16x4 o = { (bf16)v.x, (bf16)v.y, (bf16)v.z, (bf16)v.w };
            ((bf16x4*)B2)[j] = o;
        }
    } else if (bid < 3252) {
        // ---- transpose-convert route_weights: rwb[cn][l][d] = bf16(rw[cn][d][l]) ----
        int b2 = bid - 3072;
        int cn = b2 / 6, d0 = (b2 % 6) * 64;
        float (*t)[129] = (float(*)[129])shbuf;
        const float* src = rw + (size_t)cn * 384 * 128;
        #pragma unroll
        for (int p = 0; p < 8; ++p) {
            int f4 = tid + p * 256;
            int row = f4 >> 5, c4 = (f4 & 31) * 4;
            float4 v = *(const float4*)(src + (size_t)(d0 + row) * 128 + c4);
            t[row][c4] = v.x; t[row][c4 + 1] = v.y; t[row][c4 + 2] = v.z; t[row][c4 + 3] = v.w;
        }
        __syncthreads();
        bf16* dst = rwb + (size_t)cn * 128 * 384 + d0;
        #pragma unroll
        for (int p = 0; p < 4; ++p) {
            int i8 = tid + p * 256;
            int l = i8 >> 3, d8 = (i8 & 7) * 8;
            bf16x8 o;
            #pragma unroll
            for (int i = 0; i < 8; ++i) o[i] = (bf16)t[d8 + i][l];
            *(bf16x8*)(dst + (size_t)l * 384 + d8) = o;
        }
    } else if (bid < 3284) {
        // ---- fuse semantic fc1+fc2 -> bf16 Wb[32][768] + f32 bb[32] ----
        int j = bid - 3252;
        int n = j / CAP;
        if (j >= 30) {
            for (int i = tid; i < HID; i += 256) Wb[j * HID + i] = (bf16)0.f;
            if (tid == 0) bb[j] = 0.f;
            return;
        }
        float* w2 = shbuf;
        if (tid < 100) w2[tid] = sfc2_w[j * 100 + tid];
        __syncthreads();
        const float* w1 = sfc1_w + (size_t)n * 100 * HID;
        float a0 = 0, a1 = 0, a2 = 0;
        for (int k = 0; k < 100; ++k) {
            float s2 = w2[k];
            const float* r = w1 + k * HID;
            a0 += s2 * r[tid];
            a1 += s2 * r[tid + 256];
            a2 += s2 * r[tid + 512];
        }
        Wb[j * HID + tid]       = (bf16)a0;
        Wb[j * HID + tid + 256] = (bf16)a1;
        Wb[j * HID + tid + 512] = (bf16)a2;
        if (tid == 0) {
            float b = sfc2_b[j];
            for (int k = 0; k < 100; ++k) b += sfc1_b[n * 100 + k] * w2[k];
            bb[j] = b;
        }
    } else {
        // ---- gates ----
        int i = (bid - 3284) * 256 + tid;
        int t = *tptr; float sv = *s;
        if (i < ADAPT)                gfc1[i] = sigmoidf_(sv * efc1[t * ADAPT + i]);
        else if (i < ADAPT + HID)     { int j = i - ADAPT;        gfc2[j]    = sigmoidf_(sv * efc2[t * HID + j]); }
        else if (i < ADAPT + 2 * HID) { int j = i - ADAPT - HID;  glarger[j] = sigmoidf_(sv * elarger[t * HID + j]); }
    }
}

// ---------------- semantic caps via MFMA + fused squash -> bf16 semb[n][b][384] ----------------
__launch_bounds__(256)
__global__ void k_semg(const float* __restrict__ x, const bf16* __restrict__ Wb,
                       const float* __restrict__ bb, bf16* __restrict__ semb) {
    __shared__ __align__(16) bf16 As[64 * 32];
    __shared__ __align__(16) bf16 Bs[32 * 32];
    __shared__ float sem_s[64][33];
    const int tid = threadIdx.x;
    const int wave = tid >> 6, lane = tid & 63;
    const int tm = blockIdx.x;
    const int lr = lane & 15, kg = (lane >> 4) * 8;
    f32x4 acc[2] = {};

    const float* xbase = x + (size_t)(tm * 64 + (tid >> 2)) * HID + (tid & 3) * 8;
    const bf16* wbase = Wb + (size_t)(tid >> 2) * HID + (tid & 3) * 8;  // valid for tid<128
    bf16* BsW = Bs + wave * 512;

    for (int k0 = 0; k0 < HID; k0 += 32) {
        float xv[8];
        *(float4*)&xv[0] = *(const float4*)(xbase + k0);
        *(float4*)&xv[4] = *(const float4*)(xbase + k0 + 4);
        __syncthreads();
        if (tid < 128) gld16(wbase + k0, BsW);
        bf16x8 xb;
        #pragma unroll
        for (int i = 0; i < 8; ++i) xb[i] = (bf16)xv[i];
        *(bf16x8*)&As[tid * 8] = xb;
        __syncthreads();
        bf16x8 af = *(const bf16x8*)&As[(wave * 16 + lr) * 32 + kg];
        bf16x8 b0 = *(const bf16x8*)&Bs[lr * 32 + kg];
        bf16x8 b1 = *(const bf16x8*)&Bs[(16 + lr) * 32 + kg];
        acc[0] = __builtin_amdgcn_mfma_f32_16x16x32_bf16(af, b0, acc[0], 0, 0, 0);
        acc[1] = __builtin_amdgcn_mfma_f32_16x16x32_bf16(af, b1, acc[1], 0, 0, 0);
    }

    #pragma unroll
    for (int n = 0; n < 2; ++n) {
        int col = n * 16 + lr;
        float bv = bb[col];
        #pragma unroll
        for (int r = 0; r < 4; ++r) {
            int row = wave * 16 + (lane >> 4) * 4 + r;
            sem_s[row][col] = acc[n][r] + bv;
        }
    }
    __syncthreads();
    if (tid < 64) {
        int bl = tm * 64 + tid;
        int b = bl >> 7, l = bl & 127;
        float vals[30];
        float sq[3] = {0.f, 0.f, 0.f};
        #pragma unroll
        for (int j = 0; j < 30; ++j) { float v = sem_s[tid][j]; vals[j] = v; sq[j % 3] += v * v; }
        float scl[3];
        #pragma unroll
        for (int c = 0; c < 3; ++c) scl[c] = (sq[c] / (1.f + sq[c])) / sqrtf(sq[c]);
        #pragma unroll
        for (int j = 0; j < 30; ++j)
            semb[((size_t)(j / 3) * BATCH + b) * 384 + l * 3 + (j % 3)] = (bf16)(vals[j] * scl[j % 3]);
    }
}

// ---------------- priors via MFMA: 30 blocks of 128x128x384 ----------------
__launch_bounds__(256)
__global__ void k_priorsG(const bf16* __restrict__ semb, const bf16* __restrict__ rwb,
                          float* __restrict__ priors) {
    __shared__ __align__(16) bf16 As[128 * 32];
    __shared__ __align__(16) bf16 Bs[128 * 32];
    const int cn = blockIdx.x;           // c*10+n
    const int c = cn / NTASKS, n = cn % NTASKS;
    const int tid = threadIdx.x;
    const int wave = tid >> 6, lane = tid & 63;
    const int wr = wave >> 1, wc = wave & 1;
    const int lr = lane & 15, kg = (lane >> 4) * 8;
    const int K = 384;
    f32x4 acc[4][4] = {};

    const bf16* Abase = semb + ((size_t)n * BATCH + (tid >> 2)) * K + (tid & 3) * 8;
    const bf16* Bbase = rwb + ((size_t)cn * 128 + (tid >> 2)) * K + (tid & 3) * 8;
    bf16* AsW = As + wave * 512;
    bf16* BsW = Bs + wave * 512;

    for (int k0 = 0; k0 < K; k0 += 32) {
        __syncthreads();
        gld16(Abase + k0, AsW);
        gld16(Abase + k0 + (size_t)64 * K, AsW + 2048);
        gld16(Bbase + k0, BsW);
        gld16(Bbase + k0 + (size_t)64 * K, BsW + 2048);
        __syncthreads();
        bf16x8 af[4], bfr[4];
        #pragma unroll
        for (int m = 0; m < 4; ++m)
            af[m] = *(const bf16x8*)&As[(wr * 64 + m * 16 + lr) * 32 + kg];
        #pragma unroll
        for (int nn = 0; nn < 4; ++nn)
            bfr[nn] = *(const bf16x8*)&Bs[(wc * 64 + nn * 16 + lr) * 32 + kg];
        #pragma unroll
        for (int m = 0; m < 4; ++m)
            #pragma unroll
            for (int nn = 0; nn < 4; ++nn)
                acc[m][nn] = __builtin_amdgcn_mfma_f32_16x16x32_bf16(af[m], bfr[nn], acc[m][nn], 0, 0, 0);
    }

    #pragma unroll
    for (int nn = 0; nn < 4; ++nn) {
        int col = wc * 64 + nn * 16 + lr;
        #pragma unroll
        for (int m = 0; m < 4; ++m) {
            int row0 = wr * 64 + m * 16 + (lane >> 4) * 4;
            #pragma unroll
            for (int r = 0; r < 4; ++r) {
                int row = row0 + r;
                priors[(((size_t)c * BATCH + row) * NTASKS + n) * 128 + col] = acc[m][nn][r];
            }
        }
    }
}

// ---------------- dynamic routing; logits are uniform over l ----------------
__global__ void k_routing(const float* __restrict__ priors, const int* tptr,
                          float* __restrict__ vote) {
    int cb = blockIdx.x;             // c*128+b
    int lane = threadIdx.x;          // 64
    int t = *tptr;
    float p0[NTASKS], p1[NTASKS], ln[NTASKS];
    const float* pb = priors + (size_t)cb * NTASKS * 128;
    #pragma unroll
    for (int n = 0; n < NTASKS; ++n) {
        p0[n] = pb[n * 128 + lane];
        p1[n] = pb[n * 128 + 64 + lane];
        ln[n] = 0.f;
    }
    float v0 = 0.f, v1 = 0.f;
    for (int it = 0; it < 3; ++it) {
        float lm[NTASKS];
        float mx = -3.4e38f;
        #pragma unroll
        for (int n = 0; n < NTASKS; ++n) { lm[n] = (n <= t) ? ln[n] : NEGV; mx = fmaxf(mx, lm[n]); }
        float e[NTASKS], se = 0.f;
        #pragma unroll
        for (int n = 0; n < NTASKS; ++n) { e[n] = expf(lm[n] - mx); se += e[n]; }
        float inv = 1.f / se;
        v0 = 0.f; v1 = 0.f;
        #pragma unroll
        for (int n = 0; n < NTASKS; ++n) { float pr = e[n] * inv; v0 += pr * p0[n]; v1 += pr * p1[n]; }
        if (it == 2) break;
        float sq = v0 * v0 + v1 * v1;
        #pragma unroll
        for (int m = 32; m >= 1; m >>= 1) sq += __shfl_xor(sq, m);
        float scale = (sq / (1.f + sq)) / sqrtf(sq);
        float o0 = v0 * scale, o1 = v1 * scale;
        #pragma unroll
        for (int n = 0; n < NTASKS; ++n) {
            float d = p0[n] * o0 + p1[n] * o1;
            #pragma unroll
            for (int m = 32; m >= 1; m >>= 1) d += __shfl_xor(d, m);
            ln[n] = lm[n] + d;
        }
    }
    vote[(size_t)cb * 128 + lane]      = v0;
    vote[(size_t)cb * 128 + 64 + lane] = v1;
}

// ---------------- h = x + (scrambled_vote @ larger_w^T + larger_b) * glarger  -> bf16 ----------------
__global__ void k_buildH(const float* __restrict__ x, const float* __restrict__ vote,
                         const float* __restrict__ lw, const float* __restrict__ lb,
                         const float* __restrict__ glarger, bf16* __restrict__ H) {
    int idx = blockIdx.x * 256 + threadIdx.x;   // over BL*192 float4 groups
    int bl = idx / 192, h4 = (idx % 192) * 4;
    float v0 = vote[bl * 3 + 0], v1 = vote[bl * 3 + 1], v2 = vote[bl * 3 + 2];
    float xa[4];
    *(float4*)xa = ((const float4*)x)[idx];
    bf16x4 o;
    #pragma unroll
    for (int r = 0; r < 4; ++r) {
        int hid = h4 + r;
        float hv = v0 * lw[hid * 3] + v1 * lw[hid * 3 + 1] + v2 * lw[hid * 3 + 2] + lb[hid];
        o[r] = (bf16)(xa[r] + hv * glarger[hid]);
    }
    ((bf16x4*)H)[idx] = o;
}

// ====== 128x256 BK=32 GEMM: A via LDS (3x8KB), B DIRECT global->VGPR (dbuf) ======
// Mechanism: halve LDS-pipe traffic (B never touches LDS); B-frag loads are
// fully coalesced (64 lanes = 16 rows x 64B) and L2-resident (B <= 3MB).
// Iter T: [ds_read A(T) 4] [load B(T+1)->BN 4] [stage A(T+2) 1 gld16]
//         [lgkm(0)] [setprio MFMA(aF,BC)] [vmcnt(1): drains B(T+1)+A(T+1),
//         keeps A(T+2) flying] [barrier].
// VGPR: acc 64 + aF 16 + bCur 16 + bNxt 16 + addr ~14 = ~126 <= 128 (512,4).
// MODE 1: Out = bf16 [M][N].  MODE 2: Out = f32, Out = X + val, N==HID.
template <int MODE, int K, int N, int TN, int NT>
__launch_bounds__(512, 4)
__global__ void k_gemmR(const bf16* __restrict__ A, const bf16* __restrict__ Bw,
                        const float* __restrict__ bias, const float* __restrict__ gate,
                        const float* __restrict__ X, void* __restrict__ Out) {
    __shared__ __align__(16) char smem[24576];   // 3 A-bufs x 8KB (128 rows x 64B)
    const int tid = threadIdx.x;
    const int lane = tid & 63, w = tid >> 6;
    const int lr = lane & 15, kq = lane >> 4;
    const int qr = w >> 2, qc = w & 3;              // wave grid 2x4, wave tile 64x64
    const int nwg = gridDim.x, bid = blockIdx.x;
    const int cpx = nwg >> 3;                       // grid % 8 == 0 for all calls
    const int wg = (bid & 7) * cpx + (bid >> 3);
    const int tm = wg / TN, tn = wg % TN;

    // A staging (r7-verified geometry/swizzle, A only): 1 gld16/wave = 16 rows x 64B
    const int srow = lane >> 2;
    const int schunk = (lane & 3) ^ ((lane >> 3) & 3);
    const bf16* Ab = A + (size_t)(tm * 128 + w * 16 + srow) * K + schunk * 8;
    // B reg-load base: lanes cover rows (cols) qc*64+n*16+lr, 16B chunk kq
    const bf16* Bb = Bw + (size_t)(tn * 256 + qc * 64 + lr) * K + kq * 8;

    const int rsl = (kq ^ ((lr >> 1) & 3)) << 4;    // read-side swizzled 16B slot
    f32x4 acc[4][4] = {};
    bf16x8 aF[4], bCur[4], bNxt[4];

    // prologue: stage A tiles 0,1; load B tile 0; drain all
    gld16(Ab, smem + w * 1024);
    gld16(Ab + 32, smem + 8192 + w * 1024);
    #pragma unroll
    for (int n = 0; n < 4; ++n)
        bCur[n] = *(const bf16x8*)(Bb + (size_t)(n * 16) * K);
    asm volatile("s_waitcnt vmcnt(0)" ::: "memory");
    __builtin_amdgcn_s_barrier();

#define STEP(T, BC, BN)                                                            \
    {                                                                              \
        const int t_ = (T);                                                        \
        const char* ab_ = smem + (t_ % 3) * 8192;                                  \
        _Pragma("unroll")                                                          \
        for (int m = 0; m < 4; ++m)                                                \
            aF[m] = *(const bf16x8*)(ab_ + (qr * 64 + m * 16 + lr) * 64 + rsl);    \
        if (t_ + 1 < NT) {                                                         \
            _Pragma("unroll")                                                      \
            for (int n = 0; n < 4; ++n)                                            \
                BN[n] = *(const bf16x8*)(Bb + (size_t)(n * 16) * K + (t_ + 1) * 32); \
        }                                                                          \
        if (t_ + 2 < NT) gld16(Ab + (t_ + 2) * 32, smem + ((t_ + 2) % 3) * 8192 + w * 1024); \
        asm volatile("s_waitcnt lgkmcnt(0)" ::: "memory");                         \
        __builtin_amdgcn_sched_barrier(0);                                         \
        __builtin_amdgcn_s_setprio(1);                                             \
        _Pragma("unroll")                                                          \
        for (int m = 0; m < 4; ++m)                                                \
            _Pragma("unroll")                                                      \
            for (int n = 0; n < 4; ++n)                                            \
                acc[m][n] = __builtin_amdgcn_mfma_f32_16x16x32_bf16(               \
                    aF[m], BC[n], acc[m][n], 0, 0, 0);                             \
        __builtin_amdgcn_s_setprio(0);                                             \
        if (t_ + 2 < NT) asm volatile("s_waitcnt vmcnt(1)" ::: "memory");          \
        else             asm volatile("s_waitcnt vmcnt(0)" ::: "memory");          \
        __builtin_amdgcn_s_barrier();                                              \
    }

    #pragma unroll 1
    for (int T = 0; T < NT; T += 2) {       // NT even (24 / 64)
        STEP(T,     bCur, bNxt);
        STEP(T + 1, bNxt, bCur);
    }
#undef STEP

    #pragma unroll
    for (int n = 0; n < 4; ++n) {
        int col = tn * 256 + qc * 64 + n * 16 + lr;
        float bv = bias[col], gv = gate[col];
        #pragma unroll
        for (int m = 0; m < 4; ++m) {
            int row0 = tm * 128 + qr * 64 + m * 16 + kq * 4;
            #pragma unroll
            for (int r = 0; r < 4; ++r) {
                float v = fmaxf(acc[m][n][r] + bv, 0.f) * gv;
                int row = row0 + r;
                if (MODE == 1) {
                    ((bf16*)Out)[(size_t)row * N + col] = (bf16)v;
                } else {
                    size_t o = (size_t)row * HID + col;
                    ((float*)Out)[o] = X[o] + v;
                }
            }
        }
    }
}

extern "C" void kernel_launch(void* const* d_in, const int* in_sizes, int n_in,
                              void* d_out, int out_size, void* d_ws, size_t ws_size,
                              hipStream_t stream) {
    const float* x      = (const float*)d_in[0];
    const int*   t      = (const int*)  d_in[1];
    const float* s      = (const float*)d_in[2];
    const float* fc1_w  = (const float*)d_in[3];
    const float* fc1_b  = (const float*)d_in[4];
    const float* fc2_w  = (const float*)d_in[5];
    const float* fc2_b  = (const float*)d_in[6];
    const float* efc1   = (const float*)d_in[7];
    const float* efc2   = (const float*)d_in[8];
    const float* sfc1_w = (const float*)d_in[9];
    const float* sfc1_b = (const float*)d_in[10];
    const float* sfc2_w = (const float*)d_in[11];
    const float* sfc2_b = (const float*)d_in[12];
    const float* rw     = (const float*)d_in[13];
    const float* lw     = (const float*)d_in[14];
    const float* lb     = (const float*)d_in[15];
    const float* elarger= (const float*)d_in[16];

    char* ws = (char*)d_ws;
    size_t off = 0;
    auto alloc = [&](size_t b) { void* p = ws + off; off = (off + b + 255) & ~(size_t)255; return p; };
    float* gfc1    = (float*)alloc(ADAPT * 4);
    float* gfc2    = (float*)alloc(HID * 4);
    float* glarger = (float*)alloc(HID * 4);
    bf16*  Wb      = (bf16*) alloc(32 * HID * 2);
    float* bb      = (float*)alloc(32 * 4);
    bf16*  B1      = (bf16*) alloc((size_t)ADAPT * HID * 2);
    bf16*  B2      = (bf16*) alloc((size_t)ADAPT * HID * 2);
    bf16*  semb    = (bf16*) alloc((size_t)NTASKS * BATCH * 384 * 2);
    bf16*  rwb     = (bf16*) alloc((size_t)30 * 128 * 384 * 2);
    float* priors  = (float*)alloc((size_t)CAP * BATCH * NTASKS * 128 * 4);
    float* vote    = (float*)alloc((size_t)CAP * BATCH * 128 * 4);
    bf16*  H1      = (bf16*) alloc((size_t)BL * ADAPT * 2);
    bf16*  H       = (bf16*)d_out;  // stage bf16 h in the (larger) output buffer

    k_prep   <<<3298, 256, 0, stream>>>(fc1_w, fc2_w, B1, B2, rw, rwb,
                                        sfc1_w, sfc1_b, sfc2_w, sfc2_b, Wb, bb,
                                        efc1, efc2, elarger, s, t, gfc1, gfc2, glarger);
    k_semg   <<<BL / 64, 256, 0, stream>>>(x, Wb, bb, semb);
    k_priorsG<<<30, 256, 0, stream>>>(semb, rwb, priors);
    k_routing<<<CAP * BATCH, 64, 0, stream>>>(priors, t, vote);
    k_buildH <<<BL * 192 / 256, 256, 0, stream>>>(x, vote, lw, lb, glarger, H);
    // GEMM1: [16384x768] @ [2048x768]^T -> H1 (bf16)   grid 128*8=1024, NT=24
    k_gemmR<1, HID, ADAPT, 8, HID / 32><<<1024, 512, 0, stream>>>(H,  B1, fc1_b, gfc1, nullptr, H1);
    // GEMM2: [16384x2048] @ [768x2048]^T + x -> out    grid 128*3=384, NT=64
    k_gemmR<2, ADAPT, HID, 3, ADAPT / 32><<<384, 512, 0, stream>>>(H1, B2, fc2_b, gfc2, x, d_out);
}

// Round 13
// 191.425 us; speedup vs baseline: 2.3596x; 1.6822x over previous
//
#include <hip/hip_runtime.h>
#include <hip/hip_bf16.h>
#include <math.h>
#include <stdint.h>

typedef __bf16 bf16;
typedef __bf16 bf16x8 __attribute__((ext_vector_type(8)));
typedef __bf16 bf16x4 __attribute__((ext_vector_type(4)));
typedef float  f32x4  __attribute__((ext_vector_type(4)));

#define NTASKS 10
#define CAP    3
#define SEQ    128
#define HID    768
#define ADAPT  2048
#define BATCH  128
#define BL     (BATCH*SEQ)   /* 16384 */
#define NEGV   (-10000.0f)

__device__ __forceinline__ float sigmoidf_(float z) { return 1.f / (1.f + expf(-z)); }

// ---- async global->LDS, 16B per lane; LDS dest = wave-uniform base + lane*16 ----
__device__ __forceinline__ void gld16(const void* g, void* l) {
    auto gp = (const __attribute__((address_space(1))) uint32_t*)g;
    auto lp = (__attribute__((address_space(3))) uint32_t*)(uint32_t)(uintptr_t)l;
    __builtin_amdgcn_global_load_lds(gp, lp, 16, 0, 0);
}

// ========== fused prep: convert(3072) | rwT(180) | fusew(32) | gates(14) ==========
__global__ void k_prep(const float* __restrict__ fc1_w, const float* __restrict__ fc2_w,
                       bf16* __restrict__ B1, bf16* __restrict__ B2,
                       const float* __restrict__ rw, bf16* __restrict__ rwb,
                       const float* __restrict__ sfc1_w, const float* __restrict__ sfc1_b,
                       const float* __restrict__ sfc2_w, const float* __restrict__ sfc2_b,
                       bf16* __restrict__ Wb, float* __restrict__ bb,
                       const float* __restrict__ efc1, const float* __restrict__ efc2,
                       const float* __restrict__ elarger, const float* __restrict__ s,
                       const int* __restrict__ tptr,
                       float* __restrict__ gfc1, float* __restrict__ gfc2,
                       float* __restrict__ glarger) {
    __shared__ float shbuf[64 * 129];
    const int bid = blockIdx.x, tid = threadIdx.x;
    if (bid < 3072) {
        // ---- fp32 -> bf16 weight conversion ----
        int i = bid * 256 + tid;
        const int quarter = ADAPT * HID / 4;
        if (i < quarter) {
            float4 v = ((const float4*)fc1_w)[i];
            bf16x4 o = { (bf16)v.x, (bf16)v.y, (bf16)v.z, (bf16)v.w };
            ((bf16x4*)B1)[i] = o;
        } else {
            int j = i - quarter;
            float4 v = ((const float4*)fc2_w)[j];
            bf16x4 o = { (bf16)v.x, (bf16)v.y, (bf16)v.z, (bf16)v.w };
            ((bf16x4*)B2)[j] = o;
        }
    } else if (bid < 3252) {
        // ---- transpose-convert route_weights: rwb[cn][l][d] = bf16(rw[cn][d][l]) ----
        int b2 = bid - 3072;
        int cn = b2 / 6, d0 = (b2 % 6) * 64;
        float (*t)[129] = (float(*)[129])shbuf;
        const float* src = rw + (size_t)cn * 384 * 128;
        #pragma unroll
        for (int p = 0; p < 8; ++p) {
            int f4 = tid + p * 256;
            int row = f4 >> 5, c4 = (f4 & 31) * 4;
            float4 v = *(const float4*)(src + (size_t)(d0 + row) * 128 + c4);
            t[row][c4] = v.x; t[row][c4 + 1] = v.y; t[row][c4 + 2] = v.z; t[row][c4 + 3] = v.w;
        }
        __syncthreads();
        bf16* dst = rwb + (size_t)cn * 128 * 384 + d0;
        #pragma unroll
        for (int p = 0; p < 4; ++p) {
            int i8 = tid + p * 256;
            int l = i8 >> 3, d8 = (i8 & 7) * 8;
            bf16x8 o;
            #pragma unroll
            for (int i = 0; i < 8; ++i) o[i] = (bf16)t[d8 + i][l];
            *(bf16x8*)(dst + (size_t)l * 384 + d8) = o;
        }
    } else if (bid < 3284) {
        // ---- fuse semantic fc1+fc2 -> bf16 Wb[32][768] + f32 bb[32] ----
        int j = bid - 3252;
        int n = j / CAP;
        if (j >= 30) {
            for (int i = tid; i < HID; i += 256) Wb[j * HID + i] = (bf16)0.f;
            if (tid == 0) bb[j] = 0.f;
            return;
        }
        float* w2 = shbuf;
        if (tid < 100) w2[tid] = sfc2_w[j * 100 + tid];
        __syncthreads();
        const float* w1 = sfc1_w + (size_t)n * 100 * HID;
        float a0 = 0, a1 = 0, a2 = 0;
        for (int k = 0; k < 100; ++k) {
            float s2 = w2[k];
            const float* r = w1 + k * HID;
            a0 += s2 * r[tid];
            a1 += s2 * r[tid + 256];
            a2 += s2 * r[tid + 512];
        }
        Wb[j * HID + tid]       = (bf16)a0;
        Wb[j * HID + tid + 256] = (bf16)a1;
        Wb[j * HID + tid + 512] = (bf16)a2;
        if (tid == 0) {
            float b = sfc2_b[j];
            for (int k = 0; k < 100; ++k) b += sfc1_b[n * 100 + k] * w2[k];
            bb[j] = b;
        }
    } else {
        // ---- gates ----
        int i = (bid - 3284) * 256 + tid;
        int t = *tptr; float sv = *s;
        if (i < ADAPT)                gfc1[i] = sigmoidf_(sv * efc1[t * ADAPT + i]);
        else if (i < ADAPT + HID)     { int j = i - ADAPT;        gfc2[j]    = sigmoidf_(sv * efc2[t * HID + j]); }
        else if (i < ADAPT + 2 * HID) { int j = i - ADAPT - HID;  glarger[j] = sigmoidf_(sv * elarger[t * HID + j]); }
    }
}

// ---------------- semantic caps via MFMA + fused squash -> bf16 semb[n][b][384] ----------------
__launch_bounds__(256)
__global__ void k_semg(const float* __restrict__ x, const bf16* __restrict__ Wb,
                       const float* __restrict__ bb, bf16* __restrict__ semb) {
    __shared__ __align__(16) bf16 As[64 * 32];
    __shared__ __align__(16) bf16 Bs[32 * 32];
    __shared__ float sem_s[64][33];
    const int tid = threadIdx.x;
    const int wave = tid >> 6, lane = tid & 63;
    const int tm = blockIdx.x;
    const int lr = lane & 15, kg = (lane >> 4) * 8;
    f32x4 acc[2] = {};

    const float* xbase = x + (size_t)(tm * 64 + (tid >> 2)) * HID + (tid & 3) * 8;
    const bf16* wbase = Wb + (size_t)(tid >> 2) * HID + (tid & 3) * 8;  // valid for tid<128
    bf16* BsW = Bs + wave * 512;

    for (int k0 = 0; k0 < HID; k0 += 32) {
        float xv[8];
        *(float4*)&xv[0] = *(const float4*)(xbase + k0);
        *(float4*)&xv[4] = *(const float4*)(xbase + k0 + 4);
        __syncthreads();
        if (tid < 128) gld16(wbase + k0, BsW);
        bf16x8 xb;
        #pragma unroll
        for (int i = 0; i < 8; ++i) xb[i] = (bf16)xv[i];
        *(bf16x8*)&As[tid * 8] = xb;
        __syncthreads();
        bf16x8 af = *(const bf16x8*)&As[(wave * 16 + lr) * 32 + kg];
        bf16x8 b0 = *(const bf16x8*)&Bs[lr * 32 + kg];
        bf16x8 b1 = *(const bf16x8*)&Bs[(16 + lr) * 32 + kg];
        acc[0] = __builtin_amdgcn_mfma_f32_16x16x32_bf16(af, b0, acc[0], 0, 0, 0);
        acc[1] = __builtin_amdgcn_mfma_f32_16x16x32_bf16(af, b1, acc[1], 0, 0, 0);
    }

    #pragma unroll
    for (int n = 0; n < 2; ++n) {
        int col = n * 16 + lr;
        float bv = bb[col];
        #pragma unroll
        for (int r = 0; r < 4; ++r) {
            int row = wave * 16 + (lane >> 4) * 4 + r;
            sem_s[row][col] = acc[n][r] + bv;
        }
    }
    __syncthreads();
    if (tid < 64) {
        int bl = tm * 64 + tid;
        int b = bl >> 7, l = bl & 127;
        float vals[30];
        float sq[3] = {0.f, 0.f, 0.f};
        #pragma unroll
        for (int j = 0; j < 30; ++j) { float v = sem_s[tid][j]; vals[j] = v; sq[j % 3] += v * v; }
        float scl[3];
        #pragma unroll
        for (int c = 0; c < 3; ++c) scl[c] = (sq[c] / (1.f + sq[c])) / sqrtf(sq[c]);
        #pragma unroll
        for (int j = 0; j < 30; ++j)
            semb[((size_t)(j / 3) * BATCH + b) * 384 + l * 3 + (j % 3)] = (bf16)(vals[j] * scl[j % 3]);
    }
}

// ---------------- priors via MFMA: 30 blocks of 128x128x384 ----------------
__launch_bounds__(256)
__global__ void k_priorsG(const bf16* __restrict__ semb, const bf16* __restrict__ rwb,
                          float* __restrict__ priors) {
    __shared__ __align__(16) bf16 As[128 * 32];
    __shared__ __align__(16) bf16 Bs[128 * 32];
    const int cn = blockIdx.x;           // c*10+n
    const int c = cn / NTASKS, n = cn % NTASKS;
    const int tid = threadIdx.x;
    const int wave = tid >> 6, lane = tid & 63;
    const int wr = wave >> 1, wc = wave & 1;
    const int lr = lane & 15, kg = (lane >> 4) * 8;
    const int K = 384;
    f32x4 acc[4][4] = {};

    const bf16* Abase = semb + ((size_t)n * BATCH + (tid >> 2)) * K + (tid & 3) * 8;
    const bf16* Bbase = rwb + ((size_t)cn * 128 + (tid >> 2)) * K + (tid & 3) * 8;
    bf16* AsW = As + wave * 512;
    bf16* BsW = Bs + wave * 512;

    for (int k0 = 0; k0 < K; k0 += 32) {
        __syncthreads();
        gld16(Abase + k0, AsW);
        gld16(Abase + k0 + (size_t)64 * K, AsW + 2048);
        gld16(Bbase + k0, BsW);
        gld16(Bbase + k0 + (size_t)64 * K, BsW + 2048);
        __syncthreads();
        bf16x8 af[4], bfr[4];
        #pragma unroll
        for (int m = 0; m < 4; ++m)
            af[m] = *(const bf16x8*)&As[(wr * 64 + m * 16 + lr) * 32 + kg];
        #pragma unroll
        for (int nn = 0; nn < 4; ++nn)
            bfr[nn] = *(const bf16x8*)&Bs[(wc * 64 + nn * 16 + lr) * 32 + kg];
        #pragma unroll
        for (int m = 0; m < 4; ++m)
            #pragma unroll
            for (int nn = 0; nn < 4; ++nn)
                acc[m][nn] = __builtin_amdgcn_mfma_f32_16x16x32_bf16(af[m], bfr[nn], acc[m][nn], 0, 0, 0);
    }

    #pragma unroll
    for (int nn = 0; nn < 4; ++nn) {
        int col = wc * 64 + nn * 16 + lr;
        #pragma unroll
        for (int m = 0; m < 4; ++m) {
            int row0 = wr * 64 + m * 16 + (lane >> 4) * 4;
            #pragma unroll
            for (int r = 0; r < 4; ++r) {
                int row = row0 + r;
                priors[(((size_t)c * BATCH + row) * NTASKS + n) * 128 + col] = acc[m][nn][r];
            }
        }
    }
}

// ---------------- dynamic routing; logits are uniform over l ----------------
__global__ void k_routing(const float* __restrict__ priors, const int* tptr,
                          float* __restrict__ vote) {
    int cb = blockIdx.x;             // c*128+b
    int lane = threadIdx.x;          // 64
    int t = *tptr;
    float p0[NTASKS], p1[NTASKS], ln[NTASKS];
    const float* pb = priors + (size_t)cb * NTASKS * 128;
    #pragma unroll
    for (int n = 0; n < NTASKS; ++n) {
        p0[n] = pb[n * 128 + lane];
        p1[n] = pb[n * 128 + 64 + lane];
        ln[n] = 0.f;
    }
    float v0 = 0.f, v1 = 0.f;
    for (int it = 0; it < 3; ++it) {
        float lm[NTASKS];
        float mx = -3.4e38f;
        #pragma unroll
        for (int n = 0; n < NTASKS; ++n) { lm[n] = (n <= t) ? ln[n] : NEGV; mx = fmaxf(mx, lm[n]); }
        float e[NTASKS], se = 0.f;
        #pragma unroll
        for (int n = 0; n < NTASKS; ++n) { e[n] = expf(lm[n] - mx); se += e[n]; }
        float inv = 1.f / se;
        v0 = 0.f; v1 = 0.f;
        #pragma unroll
        for (int n = 0; n < NTASKS; ++n) { float pr = e[n] * inv; v0 += pr * p0[n]; v1 += pr * p1[n]; }
        if (it == 2) break;
        float sq = v0 * v0 + v1 * v1;
        #pragma unroll
        for (int m = 32; m >= 1; m >>= 1) sq += __shfl_xor(sq, m);
        float scale = (sq / (1.f + sq)) / sqrtf(sq);
        float o0 = v0 * scale, o1 = v1 * scale;
        #pragma unroll
        for (int n = 0; n < NTASKS; ++n) {
            float d = p0[n] * o0 + p1[n] * o1;
            #pragma unroll
            for (int m = 32; m >= 1; m >>= 1) d += __shfl_xor(d, m);
            ln[n] = lm[n] + d;
        }
    }
    vote[(size_t)cb * 128 + lane]      = v0;
    vote[(size_t)cb * 128 + 64 + lane] = v1;
}

// ---------------- h = x + (scrambled_vote @ larger_w^T + larger_b) * glarger  -> bf16 ----------------
__global__ void k_buildH(const float* __restrict__ x, const float* __restrict__ vote,
                         const float* __restrict__ lw, const float* __restrict__ lb,
                         const float* __restrict__ glarger, bf16* __restrict__ H) {
    int idx = blockIdx.x * 256 + threadIdx.x;   // over BL*192 float4 groups
    int bl = idx / 192, h4 = (idx % 192) * 4;
    float v0 = vote[bl * 3 + 0], v1 = vote[bl * 3 + 1], v2 = vote[bl * 3 + 2];
    float xa[4];
    *(float4*)xa = ((const float4*)x)[idx];
    bf16x4 o;
    #pragma unroll
    for (int r = 0; r < 4; ++r) {
        int hid = h4 + r;
        float hv = v0 * lw[hid * 3] + v1 * lw[hid * 3 + 1] + v2 * lw[hid * 3 + 2] + lb[hid];
        o[r] = (bf16)(xa[r] + hv * glarger[hid]);
    }
    ((bf16x4*)H)[idx] = o;
}

// ================= 128x256 BK=32 GEMM, 8 waves, 2 blocks/CU (r7 config — best measured) =================
// A: [M][K] bf16 row-major; Bw: [N][K] bf16 row-major.
// Wave (qr=w>>2, qc=w&3) owns a 64x64 output subtile -> acc[4][4] (64 VGPRs).
// LDS 48KB: A dbuf 2x8KB + B dbuf 2x16KB -> 2 blocks/CU.
// Bank swizzle: 16B chunk c ^ ((row>>1)&3) at stage-source and ds_read (verified 0 conflicts).
// MODE 1: Out = bf16 [M][N].  MODE 2: Out = f32, Out = X + val, N==HID.
template <int MODE>
__launch_bounds__(512, 4)
__global__ void k_gemmW(const bf16* __restrict__ A, const bf16* __restrict__ Bw,
                        const float* __restrict__ bias, const float* __restrict__ gate,
                        const float* __restrict__ X, void* __restrict__ Out,
                        int K, int N, int TN, int NT) {
    __shared__ __align__(16) char smem[49152];
    const int tid = threadIdx.x;
    const int lane = tid & 63, w = tid >> 6;
    const int lr = lane & 15, kq = lane >> 4;       // frag row in 16-group / k-chunk 0..3
    const int qr = w >> 2, qc = w & 3;              // wave grid 2x4
    const int nwg = gridDim.x, bid = blockIdx.x;
    const int cpx = nwg >> 3;                       // grid % 8 == 0 for all calls
    const int wg = (bid & 7) * cpx + (bid >> 3);
    const int tm = wg / TN, tn = wg % TN;

    // staging geometry: wave w covers rows w*16..w*16+15; 4 lanes per 64B row
    const int srow = lane >> 2;
    const int schunk = (lane & 3) ^ ((lane >> 3) & 3);   // inverse-swizzled source chunk
    const bf16* Ab  = A  + (size_t)(tm * 128 + w * 16 + srow) * K + schunk * 8;
    const bf16* Bb0 = Bw + (size_t)(tn * 256 + w * 16 + srow) * K + schunk * 8;
    const bf16* Bb1 = Bb0 + (size_t)128 * K;
    auto As_ = [&](int buf) { return smem + buf * 8192; };           // [0,16K)
    auto Bs_ = [&](int buf) { return smem + 16384 + buf * 16384; };  // [16K,48K)
    auto stage = [&](int k0, int buf) {                               // 3 gld16/wave
        gld16(Ab  + k0, As_(buf) + w * 1024);
        gld16(Bb0 + k0, Bs_(buf) + w * 1024);
        gld16(Bb1 + k0, Bs_(buf) + 8192 + w * 1024);
    };

    const int psw = (lr >> 1) & 3;    // read-side chunk swizzle
    f32x4 acc[4][4] = {};
    bf16x8 a[4], b[4];

    stage(0, 0);
    asm volatile("s_waitcnt vmcnt(0)" ::: "memory");
    __builtin_amdgcn_s_barrier();

    for (int T = 0; T < NT; ++T) {
        const int buf = T & 1;
        const bool more = (T + 1 < NT);
        if (more) stage((T + 1) * 32, buf ^ 1);   // issue-early: HBM latency under this tile
        const char* ab = As_(buf);
        const char* bb = Bs_(buf);
        #pragma unroll
        for (int m = 0; m < 4; ++m)
            a[m] = *(const bf16x8*)(ab + (qr * 64 + m * 16 + lr) * 64 + ((kq ^ psw) << 4));
        #pragma unroll
        for (int n = 0; n < 4; ++n)
            b[n] = *(const bf16x8*)(bb + (qc * 64 + n * 16 + lr) * 64 + ((kq ^ psw) << 4));
        asm volatile("s_waitcnt lgkmcnt(0)" ::: "memory");
        __builtin_amdgcn_sched_barrier(0);
        __builtin_amdgcn_s_setprio(1);
        #pragma unroll
        for (int m = 0; m < 4; ++m)
            #pragma unroll
            for (int n = 0; n < 4; ++n)
                acc[m][n] = __builtin_amdgcn_mfma_f32_16x16x32_bf16(a[m], b[n], acc[m][n], 0, 0, 0);
        __builtin_amdgcn_s_setprio(0);
        if (more) asm volatile("s_waitcnt vmcnt(0)" ::: "memory");
        __builtin_amdgcn_s_barrier();
    }

    #pragma unroll
    for (int n = 0; n < 4; ++n) {
        int col = tn * 256 + qc * 64 + n * 16 + lr;
        float bv = bias[col], gv = gate[col];
        #pragma unroll
        for (int m = 0; m < 4; ++m) {
            int row0 = tm * 128 + qr * 64 + m * 16 + kq * 4;
            #pragma unroll
            for (int r = 0; r < 4; ++r) {
                float v = fmaxf(acc[m][n][r] + bv, 0.f) * gv;
                int row = row0 + r;
                if (MODE == 1) {
                    ((bf16*)Out)[(size_t)row * N + col] = (bf16)v;
                } else {
                    size_t o = (size_t)row * HID + col;
                    ((float*)Out)[o] = X[o] + v;
                }
            }
        }
    }
}

extern "C" void kernel_launch(void* const* d_in, const int* in_sizes, int n_in,
                              void* d_out, int out_size, void* d_ws, size_t ws_size,
                              hipStream_t stream) {
    const float* x      = (const float*)d_in[0];
    const int*   t      = (const int*)  d_in[1];
    const float* s      = (const float*)d_in[2];
    const float* fc1_w  = (const float*)d_in[3];
    const float* fc1_b  = (const float*)d_in[4];
    const float* fc2_w  = (const float*)d_in[5];
    const float* fc2_b  = (const float*)d_in[6];
    const float* efc1   = (const float*)d_in[7];
    const float* efc2   = (const float*)d_in[8];
    const float* sfc1_w = (const float*)d_in[9];
    const float* sfc1_b = (const float*)d_in[10];
    const float* sfc2_w = (const float*)d_in[11];
    const float* sfc2_b = (const float*)d_in[12];
    const float* rw     = (const float*)d_in[13];
    const float* lw     = (const float*)d_in[14];
    const float* lb     = (const float*)d_in[15];
    const float* elarger= (const float*)d_in[16];

    char* ws = (char*)d_ws;
    size_t off = 0;
    auto alloc = [&](size_t b) { void* p = ws + off; off = (off + b + 255) & ~(size_t)255; return p; };
    float* gfc1    = (float*)alloc(ADAPT * 4);
    float* gfc2    = (float*)alloc(HID * 4);
    float* glarger = (float*)alloc(HID * 4);
    bf16*  Wb      = (bf16*) alloc(32 * HID * 2);
    float* bb      = (float*)alloc(32 * 4);
    bf16*  B1      = (bf16*) alloc((size_t)ADAPT * HID * 2);
    bf16*  B2      = (bf16*) alloc((size_t)ADAPT * HID * 2);
    bf16*  semb    = (bf16*) alloc((size_t)NTASKS * BATCH * 384 * 2);
    bf16*  rwb     = (bf16*) alloc((size_t)30 * 128 * 384 * 2);
    float* priors  = (float*)alloc((size_t)CAP * BATCH * NTASKS * 128 * 4);
    float* vote    = (float*)alloc((size_t)CAP * BATCH * 128 * 4);
    bf16*  H1      = (bf16*) alloc((size_t)BL * ADAPT * 2);
    bf16*  H       = (bf16*)d_out;  // stage bf16 h in the (larger) output buffer

    k_prep   <<<3298, 256, 0, stream>>>(fc1_w, fc2_w, B1, B2, rw, rwb,
                                        sfc1_w, sfc1_b, sfc2_w, sfc2_b, Wb, bb,
                                        efc1, efc2, elarger, s, t, gfc1, gfc2, glarger);
    k_semg   <<<BL / 64, 256, 0, stream>>>(x, Wb, bb, semb);
    k_priorsG<<<30, 256, 0, stream>>>(semb, rwb, priors);
    k_routing<<<CAP * BATCH, 64, 0, stream>>>(priors, t, vote);
    k_buildH <<<BL * 192 / 256, 256, 0, stream>>>(x, vote, lw, lb, glarger, H);
    // GEMM1: [16384x768] @ [2048x768]^T -> H1 (bf16)   grid 128*8=1024, NT=24
    k_gemmW<1><<<1024, 512, 0, stream>>>(H,  B1, fc1_b, gfc1, nullptr, H1,   HID,   ADAPT, 8, HID / 32);
    // GEMM2: [16384x2048] @ [768x2048]^T + x -> out    grid 128*3=384, NT=64
    k_gemmW<2><<<384, 512, 0, stream>>>(H1, B2, fc2_b, gfc2, x,       d_out, ADAPT, HID,  3, ADAPT / 32);
}

// Round 16
// 186.677 us; speedup vs baseline: 2.4196x; 1.0254x over previous
//
#include <hip/hip_runtime.h>
#include <hip/hip_bf16.h>
#include <math.h>
#include <stdint.h>

typedef __bf16 bf16;
typedef __bf16 bf16x8 __attribute__((ext_vector_type(8)));
typedef __bf16 bf16x4 __attribute__((ext_vector_type(4)));
typedef float  f32x4  __attribute__((ext_vector_type(4)));

#define NTASKS 10
#define CAP    3
#define SEQ    128
#define HID    768
#define ADAPT  2048
#define BATCH  128
#define BL     (BATCH*SEQ)   /* 16384 */
#define NEGV   (-10000.0f)

__device__ __forceinline__ float sigmoidf_(float z) { return 1.f / (1.f + expf(-z)); }

// ---- async global->LDS, 16B per lane; LDS dest = wave-uniform base + lane*16 ----
__device__ __forceinline__ void gld16(const void* g, void* l) {
    auto gp = (const __attribute__((address_space(1))) uint32_t*)g;
    auto lp = (__attribute__((address_space(3))) uint32_t*)(uint32_t)(uintptr_t)l;
    __builtin_amdgcn_global_load_lds(gp, lp, 16, 0, 0);
}

// ========== fused prep: convert(3072) | rwT(180) | fusew(32) | gates(14) ==========
__global__ void k_prep(const float* __restrict__ fc1_w, const float* __restrict__ fc2_w,
                       bf16* __restrict__ B1, bf16* __restrict__ B2,
                       const float* __restrict__ rw, bf16* __restrict__ rwb,
                       const float* __restrict__ sfc1_w, const float* __restrict__ sfc1_b,
                       const float* __restrict__ sfc2_w, const float* __restrict__ sfc2_b,
                       bf16* __restrict__ Wb, float* __restrict__ bb,
                       const float* __restrict__ efc1, const float* __restrict__ efc2,
                       const float* __restrict__ elarger, const float* __restrict__ s,
                       const int* __restrict__ tptr,
                       float* __restrict__ gfc1, float* __restrict__ gfc2,
                       float* __restrict__ glarger) {
    __shared__ float shbuf[64 * 129];
    const int bid = blockIdx.x, tid = threadIdx.x;
    if (bid < 3072) {
        // ---- fp32 -> bf16 weight conversion ----
        int i = bid * 256 + tid;
        const int quarter = ADAPT * HID / 4;
        if (i < quarter) {
            float4 v = ((const float4*)fc1_w)[i];
            bf16x4 o = { (bf16)v.x, (bf16)v.y, (bf16)v.z, (bf16)v.w };
            ((bf16x4*)B1)[i] = o;
        } else {
            int j = i - quarter;
            float4 v = ((const float4*)fc2_w)[j];
            bf16x4 o = { (bf16)v.x, (bf16)v.y, (bf16)v.z, (bf16)v.w };
            ((bf16x4*)B2)[j] = o;
        }
    } else if (bid < 3252) {
        // ---- transpose-convert route_weights: rwb[cn][l][d] = bf16(rw[cn][d][l]) ----
        int b2 = bid - 3072;
        int cn = b2 / 6, d0 = (b2 % 6) * 64;
        float (*t)[129] = (float(*)[129])shbuf;
        const float* src = rw + (size_t)cn * 384 * 128;
        #pragma unroll
        for (int p = 0; p < 8; ++p) {
            int f4 = tid + p * 256;
            int row = f4 >> 5, c4 = (f4 & 31) * 4;
            float4 v = *(const float4*)(src + (size_t)(d0 + row) * 128 + c4);
            t[row][c4] = v.x; t[row][c4 + 1] = v.y; t[row][c4 + 2] = v.z; t[row][c4 + 3] = v.w;
        }
        __syncthreads();
        bf16* dst = rwb + (size_t)cn * 128 * 384 + d0;
        #pragma unroll
        for (int p = 0; p < 4; ++p) {
            int i8 = tid + p * 256;
            int l = i8 >> 3, d8 = (i8 & 7) * 8;
            bf16x8 o;
            #pragma unroll
            for (int i = 0; i < 8; ++i) o[i] = (bf16)t[d8 + i][l];
            *(bf16x8*)(dst + (size_t)l * 384 + d8) = o;
        }
    } else if (bid < 3284) {
        // ---- fuse semantic fc1+fc2 -> bf16 Wb[32][768] + f32 bb[32] ----
        int j = bid - 3252;
        int n = j / CAP;
        if (j >= 30) {
            for (int i = tid; i < HID; i += 256) Wb[j * HID + i] = (bf16)0.f;
            if (tid == 0) bb[j] = 0.f;
            return;
        }
        float* w2 = shbuf;
        if (tid < 100) w2[tid] = sfc2_w[j * 100 + tid];
        __syncthreads();
        const float* w1 = sfc1_w + (size_t)n * 100 * HID;
        float a0 = 0, a1 = 0, a2 = 0;
        for (int k = 0; k < 100; ++k) {
            float s2 = w2[k];
            const float* r = w1 + k * HID;
            a0 += s2 * r[tid];
            a1 += s2 * r[tid + 256];
            a2 += s2 * r[tid + 512];
        }
        Wb[j * HID + tid]       = (bf16)a0;
        Wb[j * HID + tid + 256] = (bf16)a1;
        Wb[j * HID + tid + 512] = (bf16)a2;
        if (tid == 0) {
            float b = sfc2_b[j];
            for (int k = 0; k < 100; ++k) b += sfc1_b[n * 100 + k] * w2[k];
            bb[j] = b;
        }
    } else {
        // ---- gates ----
        int i = (bid - 3284) * 256 + tid;
        int t = *tptr; float sv = *s;
        if (i < ADAPT)                gfc1[i] = sigmoidf_(sv * efc1[t * ADAPT + i]);
        else if (i < ADAPT + HID)     { int j = i - ADAPT;        gfc2[j]    = sigmoidf_(sv * efc2[t * HID + j]); }
        else if (i < ADAPT + 2 * HID) { int j = i - ADAPT - HID;  glarger[j] = sigmoidf_(sv * elarger[t * HID + j]); }
    }
}

// ---------------- semantic caps via MFMA + fused squash -> bf16 semb[n][b][384] ----------------
__launch_bounds__(256)
__global__ void k_semg(const float* __restrict__ x, const bf16* __restrict__ Wb,
                       const float* __restrict__ bb, bf16* __restrict__ semb) {
    __shared__ __align__(16) bf16 As[64 * 32];
    __shared__ __align__(16) bf16 Bs[32 * 32];
    __shared__ float sem_s[64][33];
    const int tid = threadIdx.x;
    const int wave = tid >> 6, lane = tid & 63;
    const int tm = blockIdx.x;
    const int lr = lane & 15, kg = (lane >> 4) * 8;
    f32x4 acc[2] = {};

    const float* xbase = x + (size_t)(tm * 64 + (tid >> 2)) * HID + (tid & 3) * 8;
    const bf16* wbase = Wb + (size_t)(tid >> 2) * HID + (tid & 3) * 8;  // valid for tid<128
    bf16* BsW = Bs + wave * 512;

    for (int k0 = 0; k0 < HID; k0 += 32) {
        float xv[8];
        *(float4*)&xv[0] = *(const float4*)(xbase + k0);
        *(float4*)&xv[4] = *(const float4*)(xbase + k0 + 4);
        __syncthreads();
        if (tid < 128) gld16(wbase + k0, BsW);
        bf16x8 xb;
        #pragma unroll
        for (int i = 0; i < 8; ++i) xb[i] = (bf16)xv[i];
        *(bf16x8*)&As[tid * 8] = xb;
        __syncthreads();
        bf16x8 af = *(const bf16x8*)&As[(wave * 16 + lr) * 32 + kg];
        bf16x8 b0 = *(const bf16x8*)&Bs[lr * 32 + kg];
        bf16x8 b1 = *(const bf16x8*)&Bs[(16 + lr) * 32 + kg];
        acc[0] = __builtin_amdgcn_mfma_f32_16x16x32_bf16(af, b0, acc[0], 0, 0, 0);
        acc[1] = __builtin_amdgcn_mfma_f32_16x16x32_bf16(af, b1, acc[1], 0, 0, 0);
    }

    #pragma unroll
    for (int n = 0; n < 2; ++n) {
        int col = n * 16 + lr;
        float bv = bb[col];
        #pragma unroll
        for (int r = 0; r < 4; ++r) {
            int row = wave * 16 + (lane >> 4) * 4 + r;
            sem_s[row][col] = acc[n][r] + bv;
        }
    }
    __syncthreads();
    if (tid < 64) {
        int bl = tm * 64 + tid;
        int b = bl >> 7, l = bl & 127;
        float vals[30];
        float sq[3] = {0.f, 0.f, 0.f};
        #pragma unroll
        for (int j = 0; j < 30; ++j) { float v = sem_s[tid][j]; vals[j] = v; sq[j % 3] += v * v; }
        float scl[3];
        #pragma unroll
        for (int c = 0; c < 3; ++c) scl[c] = (sq[c] / (1.f + sq[c])) / sqrtf(sq[c]);
        #pragma unroll
        for (int j = 0; j < 30; ++j)
            semb[((size_t)(j / 3) * BATCH + b) * 384 + l * 3 + (j % 3)] = (bf16)(vals[j] * scl[j % 3]);
    }
}

// ---------------- priors via MFMA: 30 blocks of 128x128x384 ----------------
__launch_bounds__(256)
__global__ void k_priorsG(const bf16* __restrict__ semb, const bf16* __restrict__ rwb,
                          float* __restrict__ priors) {
    __shared__ __align__(16) bf16 As[128 * 32];
    __shared__ __align__(16) bf16 Bs[128 * 32];
    const int cn = blockIdx.x;           // c*10+n
    const int c = cn / NTASKS, n = cn % NTASKS;
    const int tid = threadIdx.x;
    const int wave = tid >> 6, lane = tid & 63;
    const int wr = wave >> 1, wc = wave & 1;
    const int lr = lane & 15, kg = (lane >> 4) * 8;
    const int K = 384;
    f32x4 acc[4][4] = {};

    const bf16* Abase = semb + ((size_t)n * BATCH + (tid >> 2)) * K + (tid & 3) * 8;
    const bf16* Bbase = rwb + ((size_t)cn * 128 + (tid >> 2)) * K + (tid & 3) * 8;
    bf16* AsW = As + wave * 512;
    bf16* BsW = Bs + wave * 512;

    for (int k0 = 0; k0 < K; k0 += 32) {
        __syncthreads();
        gld16(Abase + k0, AsW);
        gld16(Abase + k0 + (size_t)64 * K, AsW + 2048);
        gld16(Bbase + k0, BsW);
        gld16(Bbase + k0 + (size_t)64 * K, BsW + 2048);
        __syncthreads();
        bf16x8 af[4], bfr[4];
        #pragma unroll
        for (int m = 0; m < 4; ++m)
            af[m] = *(const bf16x8*)&As[(wr * 64 + m * 16 + lr) * 32 + kg];
        #pragma unroll
        for (int nn = 0; nn < 4; ++nn)
            bfr[nn] = *(const bf16x8*)&Bs[(wc * 64 + nn * 16 + lr) * 32 + kg];
        #pragma unroll
        for (int m = 0; m < 4; ++m)
            #pragma unroll
            for (int nn = 0; nn < 4; ++nn)
                acc[m][nn] = __builtin_amdgcn_mfma_f32_16x16x32_bf16(af[m], bfr[nn], acc[m][nn], 0, 0, 0);
    }

    #pragma unroll
    for (int nn = 0; nn < 4; ++nn) {
        int col = wc * 64 + nn * 16 + lr;
        #pragma unroll
        for (int m = 0; m < 4; ++m) {
            int row0 = wr * 64 + m * 16 + (lane >> 4) * 4;
            #pragma unroll
            for (int r = 0; r < 4; ++r) {
                int row = row0 + r;
                priors[(((size_t)c * BATCH + row) * NTASKS + n) * 128 + col] = acc[m][nn][r];
            }
        }
    }
}

// ---------------- dynamic routing; logits are uniform over l ----------------
__global__ void k_routing(const float* __restrict__ priors, const int* tptr,
                          float* __restrict__ vote) {
    int cb = blockIdx.x;             // c*128+b
    int lane = threadIdx.x;          // 64
    int t = *tptr;
    float p0[NTASKS], p1[NTASKS], ln[NTASKS];
    const float* pb = priors + (size_t)cb * NTASKS * 128;
    #pragma unroll
    for (int n = 0; n < NTASKS; ++n) {
        p0[n] = pb[n * 128 + lane];
        p1[n] = pb[n * 128 + 64 + lane];
        ln[n] = 0.f;
    }
    float v0 = 0.f, v1 = 0.f;
    for (int it = 0; it < 3; ++it) {
        float lm[NTASKS];
        float mx = -3.4e38f;
        #pragma unroll
        for (int n = 0; n < NTASKS; ++n) { lm[n] = (n <= t) ? ln[n] : NEGV; mx = fmaxf(mx, lm[n]); }
        float e[NTASKS], se = 0.f;
        #pragma unroll
        for (int n = 0; n < NTASKS; ++n) { e[n] = expf(lm[n] - mx); se += e[n]; }
        float inv = 1.f / se;
        v0 = 0.f; v1 = 0.f;
        #pragma unroll
        for (int n = 0; n < NTASKS; ++n) { float pr = e[n] * inv; v0 += pr * p0[n]; v1 += pr * p1[n]; }
        if (it == 2) break;
        float sq = v0 * v0 + v1 * v1;
        #pragma unroll
        for (int m = 32; m >= 1; m >>= 1) sq += __shfl_xor(sq, m);
        float scale = (sq / (1.f + sq)) / sqrtf(sq);
        float o0 = v0 * scale, o1 = v1 * scale;
        #pragma unroll
        for (int n = 0; n < NTASKS; ++n) {
            float d = p0[n] * o0 + p1[n] * o1;
            #pragma unroll
            for (int m = 32; m >= 1; m >>= 1) d += __shfl_xor(d, m);
            ln[n] = lm[n] + d;
        }
    }
    vote[(size_t)cb * 128 + lane]      = v0;
    vote[(size_t)cb * 128 + 64 + lane] = v1;
}

// ---------------- h = x + (scrambled_vote @ larger_w^T + larger_b) * glarger  -> bf16 ----------------
__global__ void k_buildH(const float* __restrict__ x, const float* __restrict__ vote,
                         const float* __restrict__ lw, const float* __restrict__ lb,
                         const float* __restrict__ glarger, bf16* __restrict__ H) {
    int idx = blockIdx.x * 256 + threadIdx.x;   // over BL*192 float4 groups
    int bl = idx / 192, h4 = (idx % 192) * 4;
    float v0 = vote[bl * 3 + 0], v1 = vote[bl * 3 + 1], v2 = vote[bl * 3 + 2];
    float xa[4];
    *(float4*)xa = ((const float4*)x)[idx];
    bf16x4 o;
    #pragma unroll
    for (int r = 0; r < 4; ++r) {
        int hid = h4 + r;
        float hv = v0 * lw[hid * 3] + v1 * lw[hid * 3 + 1] + v2 * lw[hid * 3 + 2] + lb[hid];
        o[r] = (bf16)(xa[r] + hv * glarger[hid]);
    }
    ((bf16x4*)H)[idx] = o;
}

// ====== 128x256 BK=32 GEMM, 4 waves x (64x128 wave-tile), 2 blocks/CU ======
// Same r7 loop skeleton + verified swizzle; wave tile fattened 64x64 -> 64x128
// to cut LDS-read bytes per MFMA-FLOP (reads 48KB vs 64KB per block-step).
// Wave w: qr=w>>1 (row 64-half), qc=w&1 (col 128-half). acc[4][8] = 128 VGPR,
// launch_bounds(256,2) -> 256 VGPR budget, LDS 48KB -> 2 blocks/CU.
// MODE 1: Out = bf16 [M][N].  MODE 2: Out = f32, Out = X + val, N==HID.
template <int MODE>
__launch_bounds__(256, 2)
__global__ void k_gemmV(const bf16* __restrict__ A, const bf16* __restrict__ Bw,
                        const float* __restrict__ bias, const float* __restrict__ gate,
                        const float* __restrict__ X, void* __restrict__ Out,
                        int K, int N, int TN, int NT) {
    __shared__ __align__(16) char smem[49152];
    const int tid = threadIdx.x;
    const int lane = tid & 63, w = tid >> 6;        // 4 waves
    const int lr = lane & 15, kq = lane >> 4;       // frag row in 16-group / k-chunk 0..3
    const int qr = w >> 1, qc = w & 1;              // wave grid 2x2, wave tile 64x128
    const int nwg = gridDim.x, bid = blockIdx.x;
    const int cpx = nwg >> 3;                       // grid % 8 == 0 for all calls
    const int wg = (bid & 7) * cpx + (bid >> 3);
    const int tm = wg / TN, tn = wg % TN;

    // staging geometry (r7-verified swizzle): each gld16 covers 16 rows x 64B;
    // A: wave w covers rows w*32..w*32+31 (2 issues); B: rows w*64..w*64+63 (4 issues).
    const int srow = lane >> 2;
    const int schunk = (lane & 3) ^ ((lane >> 3) & 3);   // inverse-swizzled source chunk
    const bf16* Ab = A  + (size_t)(tm * 128 + w * 32 + srow) * K + schunk * 8;
    const bf16* Bb = Bw + (size_t)(tn * 256 + w * 64 + srow) * K + schunk * 8;
    auto As_ = [&](int buf) { return smem + buf * 8192; };           // [0,16K)
    auto Bs_ = [&](int buf) { return smem + 16384 + buf * 16384; };  // [16K,48K)
    auto stage = [&](int k0, int buf) {                               // 6 gld16/wave
        gld16(Ab + k0,                    As_(buf) + w * 2048);
        gld16(Ab + k0 + (size_t)16 * K,   As_(buf) + w * 2048 + 1024);
        gld16(Bb + k0,                    Bs_(buf) + w * 4096);
        gld16(Bb + k0 + (size_t)16 * K,   Bs_(buf) + w * 4096 + 1024);
        gld16(Bb + k0 + (size_t)32 * K,   Bs_(buf) + w * 4096 + 2048);
        gld16(Bb + k0 + (size_t)48 * K,   Bs_(buf) + w * 4096 + 3072);
    };

    const int psw = (lr >> 1) & 3;    // read-side chunk swizzle
    f32x4 acc[4][8] = {};
    bf16x8 a[4], b[8];

    stage(0, 0);
    asm volatile("s_waitcnt vmcnt(0)" ::: "memory");
    __builtin_amdgcn_s_barrier();

    for (int T = 0; T < NT; ++T) {
        const int buf = T & 1;
        const bool more = (T + 1 < NT);
        if (more) stage((T + 1) * 32, buf ^ 1);   // issue-early: HBM latency under this tile
        const char* ab = As_(buf);
        const char* bb = Bs_(buf);
        #pragma unroll
        for (int m = 0; m < 4; ++m)
            a[m] = *(const bf16x8*)(ab + (qr * 64 + m * 16 + lr) * 64 + ((kq ^ psw) << 4));
        #pragma unroll
        for (int n = 0; n < 8; ++n)
            b[n] = *(const bf16x8*)(bb + (qc * 128 + n * 16 + lr) * 64 + ((kq ^ psw) << 4));
        asm volatile("s_waitcnt lgkmcnt(0)" ::: "memory");
        __builtin_amdgcn_sched_barrier(0);
        __builtin_amdgcn_s_setprio(1);
        #pragma unroll
        for (int m = 0; m < 4; ++m)
            #pragma unroll
            for (int n = 0; n < 8; ++n)
                acc[m][n] = __builtin_amdgcn_mfma_f32_16x16x32_bf16(a[m], b[n], acc[m][n], 0, 0, 0);
        __builtin_amdgcn_s_setprio(0);
        if (more) asm volatile("s_waitcnt vmcnt(0)" ::: "memory");
        __builtin_amdgcn_s_barrier();
    }

    #pragma unroll
    for (int n = 0; n < 8; ++n) {
        int col = tn * 256 + qc * 128 + n * 16 + lr;
        float bv = bias[col], gv = gate[col];
        #pragma unroll
        for (int m = 0; m < 4; ++m) {
            int row0 = tm * 128 + qr * 64 + m * 16 + kq * 4;
            #pragma unroll
            for (int r = 0; r < 4; ++r) {
                float v = fmaxf(acc[m][n][r] + bv, 0.f) * gv;
                int row = row0 + r;
                if (MODE == 1) {
                    ((bf16*)Out)[(size_t)row * N + col] = (bf16)v;
                } else {
                    size_t o = (size_t)row * HID + col;
                    ((float*)Out)[o] = X[o] + v;
                }
            }
        }
    }
}

extern "C" void kernel_launch(void* const* d_in, const int* in_sizes, int n_in,
                              void* d_out, int out_size, void* d_ws, size_t ws_size,
                              hipStream_t stream) {
    const float* x      = (const float*)d_in[0];
    const int*   t      = (const int*)  d_in[1];
    const float* s      = (const float*)d_in[2];
    const float* fc1_w  = (const float*)d_in[3];
    const float* fc1_b  = (const float*)d_in[4];
    const float* fc2_w  = (const float*)d_in[5];
    const float* fc2_b  = (const float*)d_in[6];
    const float* efc1   = (const float*)d_in[7];
    const float* efc2   = (const float*)d_in[8];
    const float* sfc1_w = (const float*)d_in[9];
    const float* sfc1_b = (const float*)d_in[10];
    const float* sfc2_w = (const float*)d_in[11];
    const float* sfc2_b = (const float*)d_in[12];
    const float* rw     = (const float*)d_in[13];
    const float* lw     = (const float*)d_in[14];
    const float* lb     = (const float*)d_in[15];
    const float* elarger= (const float*)d_in[16];

    char* ws = (char*)d_ws;
    size_t off = 0;
    auto alloc = [&](size_t b) { void* p = ws + off; off = (off + b + 255) & ~(size_t)255; return p; };
    float* gfc1    = (float*)alloc(ADAPT * 4);
    float* gfc2    = (float*)alloc(HID * 4);
    float* glarger = (float*)alloc(HID * 4);
    bf16*  Wb      = (bf16*) alloc(32 * HID * 2);
    float* bb      = (float*)alloc(32 * 4);
    bf16*  B1      = (bf16*) alloc((size_t)ADAPT * HID * 2);
    bf16*  B2      = (bf16*) alloc((size_t)ADAPT * HID * 2);
    bf16*  semb    = (bf16*) alloc((size_t)NTASKS * BATCH * 384 * 2);
    bf16*  rwb     = (bf16*) alloc((size_t)30 * 128 * 384 * 2);
    float* priors  = (float*)alloc((size_t)CAP * BATCH * NTASKS * 128 * 4);
    float* vote    = (float*)alloc((size_t)CAP * BATCH * 128 * 4);
    bf16*  H1      = (bf16*) alloc((size_t)BL * ADAPT * 2);
    bf16*  H       = (bf16*)d_out;  // stage bf16 h in the (larger) output buffer

    k_prep   <<<3298, 256, 0, stream>>>(fc1_w, fc2_w, B1, B2, rw, rwb,
                                        sfc1_w, sfc1_b, sfc2_w, sfc2_b, Wb, bb,
                                        efc1, efc2, elarger, s, t, gfc1, gfc2, glarger);
    k_semg   <<<BL / 64, 256, 0, stream>>>(x, Wb, bb, semb);
    k_priorsG<<<30, 256, 0, stream>>>(semb, rwb, priors);
    k_routing<<<CAP * BATCH, 64, 0, stream>>>(priors, t, vote);
    k_buildH <<<BL * 192 / 256, 256, 0, stream>>>(x, vote, lw, lb, glarger, H);
    // GEMM1: [16384x768] @ [2048x768]^T -> H1 (bf16)   grid 128*8=1024, NT=24
    k_gemmV<1><<<1024, 256, 0, stream>>>(H,  B1, fc1_b, gfc1, nullptr, H1,   HID,   ADAPT, 8, HID / 32);
    // GEMM2: [16384x2048] @ [768x2048]^T + x -> out    grid 128*3=384, NT=64
    k_gemmV<2><<<384, 256, 0, stream>>>(H1, B2, fc2_b, gfc2, x,       d_out, ADAPT, HID,  3, ADAPT / 32);
}